// Round 7
// baseline (99.914 us; speedup 1.0000x reference)
//
#include <hip/hip_runtime.h>
#include <stdint.h>

#define NROWS 8192
#define HALF_N 4096
#define DIM 512          /* elements per row; == bytes per row in fp8 */
#define INV_TEMP 2.0f
#define E2SCALE 2.8853900817779268f  /* INV_TEMP * log2(e) */
#define LN2 0.6931471805599453f
#define NTILES 528       /* 256x256 tiles: 32*33/2 */
#define NXCD 8
#define TPX (NTILES / NXCD)  /* 66; NTILES % 8 == 0 so the swizzle is bijective */

typedef int i32x8 __attribute__((ext_vector_type(8)));
typedef float f32x16 __attribute__((ext_vector_type(16)));

// global -> LDS direct copy, 16B per lane; LDS dest is wave-uniform base + lane*16
__device__ __forceinline__ void gload_lds16(const unsigned char* g, unsigned char* l) {
  __builtin_amdgcn_global_load_lds(
      (const __attribute__((address_space(1))) unsigned int*)(uintptr_t)g,
      (__attribute__((address_space(3))) unsigned int*)(uint32_t)(uintptr_t)l,
      16, 0, 0);
}

// One wave per row: sumsq -> rsqrt -> fp8 e4m3 store (4 MB). Zeroes sumexp.
__global__ void __launch_bounds__(256) k_normalize(const float* __restrict__ zi,
                                                   const float* __restrict__ zj,
                                                   unsigned char* __restrict__ zn,
                                                   float* __restrict__ sumexp) {
  int tid = threadIdx.x;
  int gid = blockIdx.x * 256 + tid;
  if (gid < NROWS) sumexp[gid] = 0.0f;
  int wave = tid >> 6, lane = tid & 63;
  int row = blockIdx.x * 4 + wave;
  const float* src = (row < HALF_N) ? (zi + (size_t)row * DIM)
                                    : (zj + (size_t)(row - HALF_N) * DIM);
  const float4* s4 = (const float4*)src;
  float4 a = s4[lane];        // cols 4*lane .. +3
  float4 b = s4[lane + 64];   // cols 256+4*lane .. +3
  float ss = a.x * a.x + a.y * a.y + a.z * a.z + a.w * a.w +
             b.x * b.x + b.y * b.y + b.z * b.z + b.w * b.w;
#pragma unroll
  for (int off = 32; off > 0; off >>= 1) ss += __shfl_xor(ss, off, 64);
  float inv = 1.0f / fmaxf(sqrtf(ss), 1e-8f);
  int w0 = __builtin_amdgcn_cvt_pk_fp8_f32(a.x * inv, a.y * inv, 0, false);
  w0 = __builtin_amdgcn_cvt_pk_fp8_f32(a.z * inv, a.w * inv, w0, true);
  int w1 = __builtin_amdgcn_cvt_pk_fp8_f32(b.x * inv, b.y * inv, 0, false);
  w1 = __builtin_amdgcn_cvt_pk_fp8_f32(b.z * inv, b.w * inv, w1, true);
  unsigned char* dst = zn + (size_t)row * DIM;
  *((int*)(dst + lane * 4)) = w0;
  *((int*)(dst + 256 + lane * 4)) = w1;
}

// R7: 8-PHASE schedule on R4's (verified-correct) 256x256 geometry.
// Per K-tile, 2 fine phases: P1 {ds_read A01+B01 || stage A(kt+2) -> bar -> lgkm(0)
// -> 4 MFMA -> bar}; P2 {ds_read A23 (B reused in regs) || stage B(kt+2) -> bar ->
// lgkm(0) -> 4 MFMA -> vmcnt(4) -> bar}. Counted vmcnt ONCE per K-tile (never 0 in
// steady state); setprio around each MFMA cluster (T5's prereq = the phase split).
// LDS/MFMA balance at this geometry (per CU-window: 128 KB LDS ~ 1000 cy vs MFMA
// 1104 cy) is right; R4 failed on schedule (6700-cy windows), not balance.
__global__ void __launch_bounds__(512, 2) k_simsum(const unsigned char* __restrict__ zn,
                                                   float* __restrict__ sumexp,
                                                   float* __restrict__ posv) {
  __shared__ __align__(16) unsigned char As[3][256 * 64];  // 3 x 16 KB
  __shared__ __align__(16) unsigned char Bs[3][256 * 64];  // 3 x 16 KB
  int tid = threadIdx.x;
  int wave = tid >> 6, lane = tid & 63;

  // XCD-aware bijective swizzle (528 = 8*66): consecutive idx share tn (B-panel).
  int bswz = (blockIdx.x & (NXCD - 1)) * TPX + (blockIdx.x >> 3);
  // triangular decode, tn-major: idx = tn(tn+1)/2 + tm, tm <= tn, tn in [0,32)
  int idx = bswz;
  int tn = (int)((sqrtf(8.0f * idx + 1.0f) - 1.0f) * 0.5f);
  while (tn * (tn + 1) / 2 > idx) tn--;
  while ((tn + 1) * (tn + 2) / 2 <= idx) tn++;
  int tm = idx - tn * (tn + 1) / 2;
  int rowBase = tm * 256, colBase = tn * 256;
  int wr = (wave >> 2) * 128, wc = (wave & 3) * 64;  // wave's 128x64 region
  int h = lane >> 5, c32 = lane & 31;                // k-half and row/col within 32-block

  // staging: wave stages 32 rows of A and B per K-tile; 16B/lane; 4 lanes per 64-B row.
  // Physical granule p of row r holds source k-chunk p ^ ((r>>1)&3).
  int rA = wave * 32 + (lane >> 2);
  int chunk = (lane & 3) ^ ((rA >> 1) & 3);
  const unsigned char* gA = zn + (size_t)(rowBase + rA) * DIM + chunk * 16;
  const unsigned char* gB = zn + (size_t)(colBase + rA) * DIM + chunk * 16;

#define STAGE_A(bf)                                         \
  do {                                                      \
    unsigned char* la = &As[bf][wave * 2048];               \
    gload_lds16(gA, la);                                    \
    gload_lds16(gA + 16 * DIM, la + 1024);                  \
    gA += 64;                                               \
  } while (0)
#define STAGE_B(bf)                                         \
  do {                                                      \
    unsigned char* lb = &Bs[bf][wave * 2048];               \
    gload_lds16(gB, lb);                                    \
    gload_lds16(gB + 16 * DIM, lb + 1024);                  \
    gB += 64;                                               \
  } while (0)
#define NOP ((void)0)

  f32x16 acc[4][2];
#pragma unroll
  for (int i = 0; i < 4; i++)
#pragma unroll
    for (int j = 0; j < 2; j++)
#pragma unroll
      for (int r = 0; r < 16; r++) acc[i][j][r] = 0.f;

  // Fragment read indices (int4 = one 16-B granule; row r at granule r*4).
  // Lane (c32,h) needs row-bytes k = h*32 + 0..31 -> granules 2h, 2h+1, XOR-swizzled.
  int sg = (c32 >> 1) & 3;
  int p0 = (2 * h) ^ sg, p1 = p0 ^ 1;
  int aIdx[4] = {(wr + c32) * 4, (wr + 32 + c32) * 4,
                 (wr + 64 + c32) * 4, (wr + 96 + c32) * 4};
  int bIdx[2] = {(wc + c32) * 4, (wc + 32 + c32) * 4};

#define PACK8(lo, hi) ((i32x8){lo.x, lo.y, lo.z, lo.w, hi.x, hi.y, hi.z, hi.w})
#define MF(a, b, c)                                                       \
  __builtin_amdgcn_mfma_scale_f32_32x32x64_f8f6f4((a), (b), (c), 0, 0,    \
                                                  0, 0x7F, 0, 0x7F)
#define ASM_VMCNT(n) asm volatile("s_waitcnt vmcnt(" #n ")" ::: "memory")

  i32x8 bf0, bf1;  // B fragments persist P1 -> P2 (LDS read once per K-tile)

  // P1: read A-rows wr..wr+63 + B-cols; stage next A; MFMA upper acc half.
#define PHASE1(BC, SA_STMT)                                              \
  do {                                                                   \
    const int4* Av = (const int4*)As[BC];                                \
    const int4* Bv = (const int4*)Bs[BC];                                \
    int4 a0l = Av[aIdx[0] + p0], a0h = Av[aIdx[0] + p1];                 \
    int4 a1l = Av[aIdx[1] + p0], a1h = Av[aIdx[1] + p1];                 \
    int4 b0l = Bv[bIdx[0] + p0], b0h = Bv[bIdx[0] + p1];                 \
    int4 b1l = Bv[bIdx[1] + p0], b1h = Bv[bIdx[1] + p1];                 \
    SA_STMT;                                                             \
    __builtin_amdgcn_sched_barrier(0);                                   \
    __builtin_amdgcn_s_barrier();                                        \
    asm volatile("s_waitcnt lgkmcnt(0)" ::: "memory");                   \
    __builtin_amdgcn_sched_barrier(0);                                   \
    i32x8 af0 = PACK8(a0l, a0h), af1 = PACK8(a1l, a1h);                  \
    bf0 = PACK8(b0l, b0h);                                               \
    bf1 = PACK8(b1l, b1h);                                               \
    __builtin_amdgcn_s_setprio(1);                                       \
    acc[0][0] = MF(af0, bf0, acc[0][0]);                                 \
    acc[0][1] = MF(af0, bf1, acc[0][1]);                                 \
    acc[1][0] = MF(af1, bf0, acc[1][0]);                                 \
    acc[1][1] = MF(af1, bf1, acc[1][1]);                                 \
    __builtin_amdgcn_s_setprio(0);                                       \
    __builtin_amdgcn_sched_barrier(0);                                   \
    __builtin_amdgcn_s_barrier();                                        \
  } while (0)

  // P2: read A-rows wr+64..wr+127; stage next B; MFMA lower half; counted vmcnt tail.
#define PHASE2(BC, SB_STMT, TAIL_STMT)                                   \
  do {                                                                   \
    const int4* Av = (const int4*)As[BC];                                \
    int4 a2l = Av[aIdx[2] + p0], a2h = Av[aIdx[2] + p1];                 \
    int4 a3l = Av[aIdx[3] + p0], a3h = Av[aIdx[3] + p1];                 \
    SB_STMT;                                                             \
    __builtin_amdgcn_sched_barrier(0);                                   \
    __builtin_amdgcn_s_barrier();                                        \
    asm volatile("s_waitcnt lgkmcnt(0)" ::: "memory");                   \
    __builtin_amdgcn_sched_barrier(0);                                   \
    i32x8 af2 = PACK8(a2l, a2h), af3 = PACK8(a3l, a3h);                  \
    __builtin_amdgcn_s_setprio(1);                                       \
    acc[2][0] = MF(af2, bf0, acc[2][0]);                                 \
    acc[2][1] = MF(af2, bf1, acc[2][1]);                                 \
    acc[3][0] = MF(af3, bf0, acc[3][0]);                                 \
    acc[3][1] = MF(af3, bf1, acc[3][1]);                                 \
    __builtin_amdgcn_s_setprio(0);                                       \
    TAIL_STMT;                                                           \
    __builtin_amdgcn_sched_barrier(0);                                   \
    __builtin_amdgcn_s_barrier();                                        \
  } while (0)

  // Prologue: stage kt0, kt1 (8 loads/thread); wait kt0 (oldest 4); barrier.
  STAGE_A(0); STAGE_B(0);
  STAGE_A(1); STAGE_B(1);
  ASM_VMCNT(4);
  __builtin_amdgcn_sched_barrier(0);
  __builtin_amdgcn_s_barrier();

  // K-tiles: buf = kt%3; stage target = (kt+2)%3. vmcnt(4) at each P2 retires kt+1's
  // loads (oldest 4 of the <=8 outstanding) while kt+2's stay in flight. Tail: kt6
  // P2 drains to 0 (kt7 landed); kt7 has no stages/vmcnt.
  PHASE1(0, STAGE_A(2)); PHASE2(0, STAGE_B(2), ASM_VMCNT(4));  // kt0
  PHASE1(1, STAGE_A(0)); PHASE2(1, STAGE_B(0), ASM_VMCNT(4));  // kt1
  PHASE1(2, STAGE_A(1)); PHASE2(2, STAGE_B(1), ASM_VMCNT(4));  // kt2
  PHASE1(0, STAGE_A(2)); PHASE2(0, STAGE_B(2), ASM_VMCNT(4));  // kt3
  PHASE1(1, STAGE_A(0)); PHASE2(1, STAGE_B(0), ASM_VMCNT(4));  // kt4
  PHASE1(2, STAGE_A(1)); PHASE2(2, STAGE_B(1), ASM_VMCNT(4));  // kt5
  PHASE1(0, NOP);        PHASE2(0, NOP,        ASM_VMCNT(0));  // kt6
  PHASE1(1, NOP);        PHASE2(1, NOP,        NOP);           // kt7

  // ---- Epilogue (R4-verbatim, verified). C/D: col=lane&31, row=(reg&3)+8*(reg>>2)+4*h.
  bool isDiag = (tm == tn);
  bool hasPos = (tn == tm + 16);
  bool diagLane = (h == ((c32 >> 2) & 1));  // lane holding row==col elems of a 32x32
  int rsel = (c32 & 3) | ((c32 >> 3) << 2); // reg with rowIn32 == c32
  int dj = 2 * (wave & 3) - 4 * (wave >> 2);

  if (diagLane) {
    if (isDiag) {
      if (dj == 0) { acc[0][0][rsel] = -1e30f; acc[1][1][rsel] = -1e30f; }
      else if (dj == 2) { acc[2][0][rsel] = -1e30f; acc[3][1][rsel] = -1e30f; }
    }
    if (hasPos) {
      if (dj == 0) {
        int gr = rowBase + wr + c32;
        float s0 = acc[0][0][rsel] * INV_TEMP, s1 = acc[1][1][rsel] * INV_TEMP;
        posv[gr] = s0; posv[gr + HALF_N] = s0;           // unique (row,col) -> race-free
        posv[gr + 32] = s1; posv[gr + 32 + HALF_N] = s1; // sim symmetric
      } else if (dj == 2) {
        int gr = rowBase + wr + 64 + c32;
        float s0 = acc[2][0][rsel] * INV_TEMP, s1 = acc[3][1][rsel] * INV_TEMP;
        posv[gr] = s0; posv[gr + HALF_N] = s0;
        posv[gr + 32] = s1; posv[gr + 32 + HALF_N] = s1;
      }
    }
  }

  // exp2 + row-partials IN PLACE: acc[i][0][r] <- e0+e1; cp[j] = col partials.
  float cp[2] = {0.f, 0.f};
#pragma unroll
  for (int i = 0; i < 4; i++)
#pragma unroll
    for (int r = 0; r < 16; r++) {
      float e0 = __builtin_amdgcn_exp2f(acc[i][0][r] * E2SCALE);
      float e1 = __builtin_amdgcn_exp2f(acc[i][1][r] * E2SCALE);
      cp[0] += e0;
      cp[1] += e1;
      acc[i][0][r] = e0 + e1;
    }

#define FOLD5(RPX)                                                 \
  do {                                                             \
    _Pragma("unroll") for (int t = 0; t < 16; t++) {               \
      float mine = (lane & 16) ? RPX(t + 16) : RPX(t);             \
      float oth = __shfl_xor((lane & 16) ? RPX(t) : RPX(t + 16), 16, 64); \
      RPX(t) = mine + oth;                                         \
    }                                                              \
    _Pragma("unroll") for (int t = 0; t < 8; t++) {                \
      float mine = (lane & 8) ? RPX(t + 8) : RPX(t);               \
      float oth = __shfl_xor((lane & 8) ? RPX(t) : RPX(t + 8), 8, 64); \
      RPX(t) = mine + oth;                                         \
    }                                                              \
    _Pragma("unroll") for (int t = 0; t < 4; t++) {                \
      float mine = (lane & 4) ? RPX(t + 4) : RPX(t);               \
      float oth = __shfl_xor((lane & 4) ? RPX(t) : RPX(t + 4), 4, 64); \
      RPX(t) = mine + oth;                                         \
    }                                                              \
    _Pragma("unroll") for (int t = 0; t < 2; t++) {                \
      float mine = (lane & 2) ? RPX(t + 2) : RPX(t);               \
      float oth = __shfl_xor((lane & 2) ? RPX(t) : RPX(t + 2), 2, 64); \
      RPX(t) = mine + oth;                                         \
    }                                                              \
    {                                                              \
      float mine = (lane & 1) ? RPX(1) : RPX(0);                   \
      float oth = __shfl_xor((lane & 1) ? RPX(0) : RPX(1), 1, 64); \
      RPX(0) = mine + oth;                                         \
    }                                                              \
  } while (0)

#define RPA(t) acc[(t) >> 4][0][(t) & 15]
#define RPB(t) acc[2 + ((t) >> 4)][0][(t) & 15]
  int myrow = rowBase + wr + 32 * (c32 >> 4) + (c32 & 3) + 8 * ((c32 >> 2) & 3) + 4 * h;
  FOLD5(RPA);                               // i-tiles 0,1: rows wr .. wr+63
  atomicAdd(&sumexp[myrow], RPA(0));
  FOLD5(RPB);                               // i-tiles 2,3: rows wr+64 .. wr+127
  atomicAdd(&sumexp[myrow + 64], RPB(0));
#undef RPA
#undef RPB

  if (!isDiag) {
    // col sums: combine the two k-halves' rows, then lane-half h picks col-block j=h
    cp[0] += __shfl_xor(cp[0], 32, 64);
    cp[1] += __shfl_xor(cp[1], 32, 64);
    float cv = h ? cp[1] : cp[0];
    atomicAdd(&sumexp[colBase + wc + h * 32 + c32], cv);
  }
#undef STAGE_A
#undef STAGE_B
#undef NOP
#undef PACK8
#undef MF
#undef ASM_VMCNT
#undef PHASE1
#undef PHASE2
#undef FOLD5
}

__global__ void __launch_bounds__(1024) k_final(const float* __restrict__ sumexp,
                                                const float* __restrict__ posv,
                                                float* __restrict__ out) {
  __shared__ float red[16];
  int tid = threadIdx.x;
  const float4* se4 = (const float4*)sumexp;
  const float4* pv4 = (const float4*)posv;
  float p = 0.f;
#pragma unroll
  for (int c = 0; c < 2; c++) {
    float4 se = se4[tid * 2 + c];
    float4 pv = pv4[tid * 2 + c];
    p += (__builtin_amdgcn_logf(se.x) + __builtin_amdgcn_logf(se.y) +
          __builtin_amdgcn_logf(se.z) + __builtin_amdgcn_logf(se.w)) * LN2 -
         (pv.x + pv.y + pv.z + pv.w);
  }
#pragma unroll
  for (int off = 32; off > 0; off >>= 1) p += __shfl_xor(p, off, 64);
  int wv = tid >> 6, ln = tid & 63;
  if (ln == 0) red[wv] = p;
  __syncthreads();
  if (tid == 0) {
    float t = 0.f;
    for (int w = 0; w < 16; w++) t += red[w];
    out[0] = t / (float)NROWS;
  }
}

extern "C" void kernel_launch(void* const* d_in, const int* in_sizes, int n_in,
                              void* d_out, int out_size, void* d_ws, size_t ws_size,
                              hipStream_t stream) {
  const float* zi = (const float*)d_in[0];
  const float* zj = (const float*)d_in[1];
  unsigned char* zn = (unsigned char*)d_ws;                           // 4 MB fp8
  float* sumexp = (float*)((char*)d_ws + (size_t)NROWS * DIM);        // 32 KB
  float* posv = sumexp + NROWS;                                       // 32 KB
  float* out = (float*)d_out;

  hipLaunchKernelGGL(k_normalize, dim3(2048), dim3(256), 0, stream, zi, zj, zn, sumexp);
  hipLaunchKernelGGL(k_simsum, dim3(NTILES), dim3(512), 0, stream, zn, sumexp, posv);
  hipLaunchKernelGGL(k_final, dim3(1), dim3(1024), 0, stream, sumexp, posv, out);
}